// Round 5
// baseline (241.679 us; speedup 1.0000x reference)
//
#include <hip/hip_runtime.h>

#define NOUT 7
#define NROI 512
#define NCH 256
#define BINS (NOUT * NOUT)        // 49
#define ROI_ELEMS (NCH * BINS)    // 12544
#define PAIR_EL (NCH / 2 * BINS)  // 6272 (channel-pair, bin) items per roi
#define NCHUNK ((PAIR_EL + 255) / 256)  // 25

// float4 with 4-byte alignment: dword-aligned but not 16B-aligned loads
// (gfx950 handles this; validated in an earlier session).
typedef float f4u __attribute__((ext_vector_type(4), aligned(4)));

__global__ __launch_bounds__(256, 4) void roi_pool_kernel(
    const float* __restrict__ x2,
    const float* __restrict__ x3,
    const float* __restrict__ x4,
    const float* __restrict__ x5,
    const float* __restrict__ boxes,
    float* __restrict__ out)
{
    const int r = blockIdx.x;      // roi 0..511 (or streamer id)
    const int t = threadIdx.x;     // 0..255

    // ---- streamer slice: prime the memory-side Infinity Cache in address
    // order. Dispatched first (y==0, x-fastest). Pure warm-up: no output,
    // no correctness dependency; converts the compulsory 148 MB of HBM
    // first-touch traffic from scattered 64-128B demand misses (~2.5 TB/s)
    // into sequential streams (~6.3 TB/s). Gathers then hit L3.
    if (blockIdx.y == 0) {
        const int sid = r * 256 + t;            // 0..131071
        const int NS  = NROI * 256;             // 131072 streaming threads
        float4 acc = make_float4(0.f, 0.f, 0.f, 0.f);
        const float* arrs[4] = { x2, x3, x4, x5 };
        const size_t n4[4] = { 2ull * NCH * 200 * 304 / 4,
                               2ull * NCH * 100 * 152 / 4,
                               2ull * NCH * 50  * 76  / 4,
                               2ull * NCH * 25  * 38  / 4 };
        #pragma unroll
        for (int a = 0; a < 4; ++a) {
            const float4* p = (const float4*)arrs[a];
            for (size_t i = (size_t)sid; i < n4[a]; i += NS) {
                const float4 v = p[i];
                acc.x += v.x; acc.y += v.y; acc.z += v.z; acc.w += v.w;
            }
        }
        // keep the loads live without writing anything
        asm volatile("" :: "v"(acc.x), "v"(acc.y), "v"(acc.z), "v"(acc.w));
        return;
    }

    const int chunk = blockIdx.y - 1;  // 0..24

    // y (per ph): sdyA = { asfloat(y0a*W), asfloat(y0b*W), rw0, rw1 },
    //             sdyB = { rw2, rw3 }   rw = 0.25*valid_y*{1-fy, fy} per sample
    // x fast (per pw): sdxW = xw[4] (both samples' lerp+valid weights in a
    //                  4-wide span), sdxC = span base xb
    // x slow (per pw): sdxP = { asfloat(ia), asfloat(ib), wa0, wa1 },
    //                  sdxQ = { wb0, wb1 }   (2-tap weights per x-sample)
    __shared__ float4 sdyA[NOUT];
    __shared__ float2 sdyB[NOUT];
    __shared__ float4 sdxW[NOUT];
    __shared__ int    sdxC[NOUT];
    __shared__ float4 sdxP[NOUT];
    __shared__ float2 sdxQ[NOUT];
    __shared__ int sfast;
    __shared__ const float* sbase;   // feat + b*C*H*W
    __shared__ int sW, sHW;

    if (t < 32) {
        const float bx1 = boxes[4 * r + 0];
        const float by1 = boxes[4 * r + 1];
        const float bx2 = boxes[4 * r + 2];
        const float by2 = boxes[4 * r + 3];
        const float sz  = sqrtf((bx2 - bx1) * (by2 - by1));
        float lvlf = floorf(4.0f + log2f(sz / 224.0f + 1e-8f));
        lvlf = fminf(fmaxf(lvlf, 2.0f), 5.0f);
        const int level = (int)lvlf - 2;

        int H, W; float scale; const float* feat;
        if (level == 0)      { H = 200; W = 304; scale = 0.25f;    feat = x2; }
        else if (level == 1) { H = 100; W = 152; scale = 0.125f;   feat = x3; }
        else if (level == 2) { H = 50;  W = 76;  scale = 0.0625f;  feat = x4; }
        else                 { H = 25;  W = 38;  scale = 0.03125f; feat = x5; }

        const float X1 = bx1 * scale - 0.5f;
        const float Y1 = by1 * scale - 0.5f;
        const float X2 = bx2 * scale - 0.5f;
        const float Y2 = by2 * scale - 0.5f;
        const float bw = (X2 - X1) * (1.0f / NOUT);
        const float bh = (Y2 - Y1) * (1.0f / NOUT);

        bool okl = true;   // per-lane fast-path fitness (x lanes only)

        if (t < NOUT) {
            // y descriptors for output row ph = t (samples at ph+0.25, ph+0.75)
            const int ph = t;
            float ca = Y1 + ((float)ph + 0.25f) * bh;
            float cb = Y1 + ((float)ph + 0.75f) * bh;
            const float va = ((ca >= -1.0f) && (ca <= (float)H)) ? 0.25f : 0.0f;
            const float vb = ((cb >= -1.0f) && (cb <= (float)H)) ? 0.25f : 0.0f;
            ca = fminf(fmaxf(ca, 0.0f), (float)(H - 1));
            cb = fminf(fmaxf(cb, 0.0f), (float)(H - 1));
            const int ia = min((int)floorf(ca), H - 2);   // i1 = i0+1 normalization
            const int ib = min((int)floorf(cb), H - 2);
            const float fya = ca - (float)ia;
            const float fyb = cb - (float)ib;
            sdyA[ph] = make_float4(__int_as_float(ia * W), __int_as_float(ib * W),
                                   va * (1.0f - fya), va * fya);
            sdyB[ph] = make_float2(vb * (1.0f - fyb), vb * fyb);
        } else if (t >= 8 && t < 8 + NOUT) {
            // x descriptors for output col pw = t-8
            const int pw = t - 8;
            float ca = X1 + ((float)pw + 0.25f) * bw;
            float cb = X1 + ((float)pw + 0.75f) * bw;
            const float va = ((ca >= -1.0f) && (ca <= (float)W)) ? 1.0f : 0.0f;
            const float vb = ((cb >= -1.0f) && (cb <= (float)W)) ? 1.0f : 0.0f;
            ca = fminf(fmaxf(ca, 0.0f), (float)(W - 1));
            cb = fminf(fmaxf(cb, 0.0f), (float)(W - 1));
            const int ia = min((int)floorf(ca), W - 2);
            const int ib = min((int)floorf(cb), W - 2);
            const float fxa = ca - (float)ia;
            const float fxb = cb - (float)ib;

            // slow-path descriptors (always valid)
            sdxP[pw] = make_float4(__int_as_float(ia), __int_as_float(ib),
                                   va * (1.0f - fxa), va * fxa);
            sdxQ[pw] = make_float2(vb * (1.0f - fxb), vb * fxb);

            // fast-path descriptors (valid iff both patches fit [xb, xb+3])
            const int xb = min(ia, W - 4);
            const int d0 = ia - xb;          // 0..2
            const int d1 = ib - xb;          // >= d0; fast iff <= 2
            okl = (d1 <= 2);
            float xw[4];
            #pragma unroll
            for (int k = 0; k < 4; ++k) {
                float w = 0.0f;
                w += va * ((k == d0) ? (1.0f - fxa) : (k == d0 + 1) ? fxa : 0.0f);
                w += vb * ((k == d1) ? (1.0f - fxb) : (k == d1 + 1) ? fxb : 0.0f);
                xw[k] = w;
            }
            sdxW[pw] = make_float4(xw[0], xw[1], xw[2], xw[3]);
            sdxC[pw] = xb;
        }

        // collect per-pw fitness (lanes 8..14); inactive lanes contribute 0
        const unsigned long long bal = __ballot(okl);
        if (t == 31) {
            const int b = r >> 8;
            sbase = feat + (size_t)b * NCH * H * W;
            sW    = W;
            sHW   = H * W;
            sfast = (((bal >> 8) & 0x7Full) == 0x7Full);
        }
    }
    __syncthreads();

    const int j = chunk * 256 + t;          // (channel-pair, bin) index
    if (j >= PAIR_EL) return;

    const float* const base = sbase;
    const int W  = sW;
    const int HW = sHW;

    const int cp  = j / BINS;               // channel pair 0..127
    const int bin = j - cp * BINS;          // 0..48
    const int ph  = bin / NOUT;
    const int pw  = bin - ph * NOUT;

    const float4 yA = sdyA[ph];
    const float2 yB = sdyB[ph];

    const float* const f0 = base + (size_t)(2 * cp) * HW;   // channel c
    const float* const pa = f0 + __float_as_int(yA.x);      // row y0a, chan c
    const float* const pb = f0 + __float_as_int(yA.y);      // row y0b, chan c
    // channel c+1 rows are pa+HW / pb+HW

    float o0, o1;
    if (sfast) {
        const float4 xw = sdxW[pw];
        const int    xb = sdxC[pw];
        // 8 independent 16B loads in flight (no arrays -> no scratch)
        const f4u A0 = *(const f4u*)(pa + xb);
        const f4u A1 = *(const f4u*)(pa + W + xb);
        const f4u A2 = *(const f4u*)(pb + xb);
        const f4u A3 = *(const f4u*)(pb + W + xb);
        const f4u B0 = *(const f4u*)(pa + HW + xb);
        const f4u B1 = *(const f4u*)(pa + HW + W + xb);
        const f4u B2 = *(const f4u*)(pb + HW + xb);
        const f4u B3 = *(const f4u*)(pb + HW + W + xb);
        const float dA0 = A0.x * xw.x + A0.y * xw.y + A0.z * xw.z + A0.w * xw.w;
        const float dA1 = A1.x * xw.x + A1.y * xw.y + A1.z * xw.z + A1.w * xw.w;
        const float dA2 = A2.x * xw.x + A2.y * xw.y + A2.z * xw.z + A2.w * xw.w;
        const float dA3 = A3.x * xw.x + A3.y * xw.y + A3.z * xw.z + A3.w * xw.w;
        const float dB0 = B0.x * xw.x + B0.y * xw.y + B0.z * xw.z + B0.w * xw.w;
        const float dB1 = B1.x * xw.x + B1.y * xw.y + B1.z * xw.z + B1.w * xw.w;
        const float dB2 = B2.x * xw.x + B2.y * xw.y + B2.z * xw.z + B2.w * xw.w;
        const float dB3 = B3.x * xw.x + B3.y * xw.y + B3.z * xw.z + B3.w * xw.w;
        o0 = yA.z * dA0 + yA.w * dA1 + yB.x * dA2 + yB.y * dA3;
        o1 = yA.z * dB0 + yA.w * dB1 + yB.x * dB2 + yB.y * dB3;
    } else {
        const float4 xp = sdxP[pw];
        const float2 xq = sdxQ[pw];
        const int ia = __float_as_int(xp.x);
        const int ib = __float_as_int(xp.y);
        const float2 a0 = *(const float2*)(pa + ia);
        const float2 b0 = *(const float2*)(pa + ib);
        const float2 a1 = *(const float2*)(pa + W + ia);
        const float2 b1 = *(const float2*)(pa + W + ib);
        const float2 a2 = *(const float2*)(pb + ia);
        const float2 b2 = *(const float2*)(pb + ib);
        const float2 a3 = *(const float2*)(pb + W + ia);
        const float2 b3 = *(const float2*)(pb + W + ib);
        const float2 c0 = *(const float2*)(pa + HW + ia);
        const float2 e0 = *(const float2*)(pa + HW + ib);
        const float2 c1 = *(const float2*)(pa + HW + W + ia);
        const float2 e1 = *(const float2*)(pa + HW + W + ib);
        const float2 c2 = *(const float2*)(pb + HW + ia);
        const float2 e2 = *(const float2*)(pb + HW + ib);
        const float2 c3 = *(const float2*)(pb + HW + W + ia);
        const float2 e3 = *(const float2*)(pb + HW + W + ib);
        const float dA0 = a0.x * xp.z + a0.y * xp.w + b0.x * xq.x + b0.y * xq.y;
        const float dA1 = a1.x * xp.z + a1.y * xp.w + b1.x * xq.x + b1.y * xq.y;
        const float dA2 = a2.x * xp.z + a2.y * xp.w + b2.x * xq.x + b2.y * xq.y;
        const float dA3 = a3.x * xp.z + a3.y * xp.w + b3.x * xq.x + b3.y * xq.y;
        const float dB0 = c0.x * xp.z + c0.y * xp.w + e0.x * xq.x + e0.y * xq.y;
        const float dB1 = c1.x * xp.z + c1.y * xp.w + e1.x * xq.x + e1.y * xq.y;
        const float dB2 = c2.x * xp.z + c2.y * xp.w + e2.x * xq.x + e2.y * xq.y;
        const float dB3 = c3.x * xp.z + c3.y * xp.w + e3.x * xq.x + e3.y * xq.y;
        o0 = yA.z * dA0 + yA.w * dA1 + yB.x * dA2 + yB.y * dA3;
        o1 = yA.z * dB0 + yA.w * dB1 + yB.x * dB2 + yB.y * dB3;
    }

    // out[(r, 2cp, bin)] and out[(r, 2cp+1, bin)]
    float* const obase = out + (size_t)r * ROI_ELEMS + (size_t)(2 * cp) * BINS + bin;
    obase[0]    = o0;
    obase[BINS] = o1;
}

extern "C" void kernel_launch(void* const* d_in, const int* in_sizes, int n_in,
                              void* d_out, int out_size, void* d_ws, size_t ws_size,
                              hipStream_t stream) {
    const float* x2    = (const float*)d_in[0];
    const float* x3    = (const float*)d_in[1];
    const float* x4    = (const float*)d_in[2];
    const float* x5    = (const float*)d_in[3];
    const float* boxes = (const float*)d_in[4];
    float* out = (float*)d_out;

    // y == 0 -> 512 streamer blocks (dispatched first, x-fastest order),
    // y in 1..25 -> gather chunks.
    dim3 grid(NROI, NCHUNK + 1);
    roi_pool_kernel<<<grid, 256, 0, stream>>>(x2, x3, x4, x5, boxes, out);
}

// Round 6
// 230.203 us; speedup vs baseline: 1.0499x; 1.0499x over previous
//
#include <hip/hip_runtime.h>

#define NOUT 7
#define NROI 512
#define NCH 256
#define BINS (NOUT * NOUT)        // 49
#define ROI_ELEMS (NCH * BINS)    // 12544
#define PAIR_EL (NCH / 2 * BINS)  // 6272 (channel-pair, bin) items per roi
#define NCHUNK ((PAIR_EL + 255) / 256)  // 25

// float4 with 4-byte alignment: dword-aligned but not 16B-aligned loads
// (gfx950 handles this; validated in an earlier session).
typedef float f4u __attribute__((ext_vector_type(4), aligned(4)));

__global__ __launch_bounds__(256, 4) void roi_pool_kernel(
    const float* __restrict__ x2,
    const float* __restrict__ x3,
    const float* __restrict__ x4,
    const float* __restrict__ x5,
    const float* __restrict__ boxes,
    float* __restrict__ out)
{
    const int r     = blockIdx.x;  // roi 0..511
    const int chunk = blockIdx.y;  // 0..24
    const int t     = threadIdx.x; // 0..255

    // y (per ph): sdyA = { asfloat(y0a*W), asfloat(y0b*W), rw0, rw1 },
    //             sdyB = { rw2, rw3 }   rw = 0.25*valid_y*{1-fy, fy} per sample
    // x fast (per pw): sdxW = xw[4] (both samples' lerp+valid weights in a
    //                  4-wide span), sdxC = span base xb
    // x slow (per pw): sdxP = { asfloat(ia), asfloat(ib), wa0, wa1 },
    //                  sdxQ = { wb0, wb1 }   (2-tap weights per x-sample)
    __shared__ float4 sdyA[NOUT];
    __shared__ float2 sdyB[NOUT];
    __shared__ float4 sdxW[NOUT];
    __shared__ int    sdxC[NOUT];
    __shared__ float4 sdxP[NOUT];
    __shared__ float2 sdxQ[NOUT];
    __shared__ int sfast;
    __shared__ const float* sbase;   // feat + b*C*H*W
    __shared__ int sW, sHW;

    if (t < 32) {
        const float bx1 = boxes[4 * r + 0];
        const float by1 = boxes[4 * r + 1];
        const float bx2 = boxes[4 * r + 2];
        const float by2 = boxes[4 * r + 3];
        const float sz  = sqrtf((bx2 - bx1) * (by2 - by1));
        float lvlf = floorf(4.0f + log2f(sz / 224.0f + 1e-8f));
        lvlf = fminf(fmaxf(lvlf, 2.0f), 5.0f);
        const int level = (int)lvlf - 2;

        int H, W; float scale; const float* feat;
        if (level == 0)      { H = 200; W = 304; scale = 0.25f;    feat = x2; }
        else if (level == 1) { H = 100; W = 152; scale = 0.125f;   feat = x3; }
        else if (level == 2) { H = 50;  W = 76;  scale = 0.0625f;  feat = x4; }
        else                 { H = 25;  W = 38;  scale = 0.03125f; feat = x5; }

        const float X1 = bx1 * scale - 0.5f;
        const float Y1 = by1 * scale - 0.5f;
        const float X2 = bx2 * scale - 0.5f;
        const float Y2 = by2 * scale - 0.5f;
        const float bw = (X2 - X1) * (1.0f / NOUT);
        const float bh = (Y2 - Y1) * (1.0f / NOUT);

        bool okl = true;   // per-lane fast-path fitness (x lanes only)

        if (t < NOUT) {
            // y descriptors for output row ph = t (samples at ph+0.25, ph+0.75)
            const int ph = t;
            float ca = Y1 + ((float)ph + 0.25f) * bh;
            float cb = Y1 + ((float)ph + 0.75f) * bh;
            const float va = ((ca >= -1.0f) && (ca <= (float)H)) ? 0.25f : 0.0f;
            const float vb = ((cb >= -1.0f) && (cb <= (float)H)) ? 0.25f : 0.0f;
            ca = fminf(fmaxf(ca, 0.0f), (float)(H - 1));
            cb = fminf(fmaxf(cb, 0.0f), (float)(H - 1));
            const int ia = min((int)floorf(ca), H - 2);   // i1 = i0+1 normalization
            const int ib = min((int)floorf(cb), H - 2);
            const float fya = ca - (float)ia;
            const float fyb = cb - (float)ib;
            sdyA[ph] = make_float4(__int_as_float(ia * W), __int_as_float(ib * W),
                                   va * (1.0f - fya), va * fya);
            sdyB[ph] = make_float2(vb * (1.0f - fyb), vb * fyb);
        } else if (t >= 8 && t < 8 + NOUT) {
            // x descriptors for output col pw = t-8
            const int pw = t - 8;
            float ca = X1 + ((float)pw + 0.25f) * bw;
            float cb = X1 + ((float)pw + 0.75f) * bw;
            const float va = ((ca >= -1.0f) && (ca <= (float)W)) ? 1.0f : 0.0f;
            const float vb = ((cb >= -1.0f) && (cb <= (float)W)) ? 1.0f : 0.0f;
            ca = fminf(fmaxf(ca, 0.0f), (float)(W - 1));
            cb = fminf(fmaxf(cb, 0.0f), (float)(W - 1));
            const int ia = min((int)floorf(ca), W - 2);
            const int ib = min((int)floorf(cb), W - 2);
            const float fxa = ca - (float)ia;
            const float fxb = cb - (float)ib;

            // slow-path descriptors (always valid)
            sdxP[pw] = make_float4(__int_as_float(ia), __int_as_float(ib),
                                   va * (1.0f - fxa), va * fxa);
            sdxQ[pw] = make_float2(vb * (1.0f - fxb), vb * fxb);

            // fast-path descriptors (valid iff both patches fit [xb, xb+3])
            const int xb = min(ia, W - 4);
            const int d0 = ia - xb;          // 0..2
            const int d1 = ib - xb;          // >= d0; fast iff <= 2
            okl = (d1 <= 2);
            float xw[4];
            #pragma unroll
            for (int k = 0; k < 4; ++k) {
                float w = 0.0f;
                w += va * ((k == d0) ? (1.0f - fxa) : (k == d0 + 1) ? fxa : 0.0f);
                w += vb * ((k == d1) ? (1.0f - fxb) : (k == d1 + 1) ? fxb : 0.0f);
                xw[k] = w;
            }
            sdxW[pw] = make_float4(xw[0], xw[1], xw[2], xw[3]);
            sdxC[pw] = xb;
        }

        // collect per-pw fitness (lanes 8..14); inactive lanes contribute 0
        const unsigned long long bal = __ballot(okl);
        if (t == 31) {
            const int b = r >> 8;
            sbase = feat + (size_t)b * NCH * H * W;
            sW    = W;
            sHW   = H * W;
            sfast = (((bal >> 8) & 0x7Full) == 0x7Full);
        }
    }
    __syncthreads();

    const int j = chunk * 256 + t;          // (channel-pair, bin) index
    if (j >= PAIR_EL) return;

    const float* const base = sbase;
    const int W  = sW;
    const int HW = sHW;

    const int cp  = j / BINS;               // channel pair 0..127
    const int bin = j - cp * BINS;          // 0..48
    const int ph  = bin / NOUT;
    const int pw  = bin - ph * NOUT;

    const float4 yA = sdyA[ph];
    const float2 yB = sdyB[ph];

    const float* const f0 = base + (size_t)(2 * cp) * HW;   // channel c
    const float* const pa = f0 + __float_as_int(yA.x);      // row y0a, chan c
    const float* const pb = f0 + __float_as_int(yA.y);      // row y0b, chan c
    // channel c+1 rows are pa+HW / pb+HW

    float o0, o1;
    if (sfast) {
        const float4 xw = sdxW[pw];
        const int    xb = sdxC[pw];
        // Issue all 8 independent 16B loads, THEN compute. The sched_barrier
        // forbids the scheduler from sinking loads down to their uses (R5
        // evidence: without it, VGPR_Count=28 -> ~1-2 loads in flight ->
        // 2.4 TB/s Little's-law ceiling). All 8 live across the barrier.
        const f4u A0 = *(const f4u*)(pa + xb);
        const f4u A1 = *(const f4u*)(pa + W + xb);
        const f4u A2 = *(const f4u*)(pb + xb);
        const f4u A3 = *(const f4u*)(pb + W + xb);
        const f4u B0 = *(const f4u*)(pa + HW + xb);
        const f4u B1 = *(const f4u*)(pa + HW + W + xb);
        const f4u B2 = *(const f4u*)(pb + HW + xb);
        const f4u B3 = *(const f4u*)(pb + HW + W + xb);
        __builtin_amdgcn_sched_barrier(0);
        const float dA0 = A0.x * xw.x + A0.y * xw.y + A0.z * xw.z + A0.w * xw.w;
        const float dA1 = A1.x * xw.x + A1.y * xw.y + A1.z * xw.z + A1.w * xw.w;
        const float dA2 = A2.x * xw.x + A2.y * xw.y + A2.z * xw.z + A2.w * xw.w;
        const float dA3 = A3.x * xw.x + A3.y * xw.y + A3.z * xw.z + A3.w * xw.w;
        const float dB0 = B0.x * xw.x + B0.y * xw.y + B0.z * xw.z + B0.w * xw.w;
        const float dB1 = B1.x * xw.x + B1.y * xw.y + B1.z * xw.z + B1.w * xw.w;
        const float dB2 = B2.x * xw.x + B2.y * xw.y + B2.z * xw.z + B2.w * xw.w;
        const float dB3 = B3.x * xw.x + B3.y * xw.y + B3.z * xw.z + B3.w * xw.w;
        o0 = yA.z * dA0 + yA.w * dA1 + yB.x * dA2 + yB.y * dA3;
        o1 = yA.z * dB0 + yA.w * dB1 + yB.x * dB2 + yB.y * dB3;
    } else {
        const float4 xp = sdxP[pw];
        const float2 xq = sdxQ[pw];
        const int ia = __float_as_int(xp.x);
        const int ib = __float_as_int(xp.y);
        const float2 a0 = *(const float2*)(pa + ia);
        const float2 b0 = *(const float2*)(pa + ib);
        const float2 a1 = *(const float2*)(pa + W + ia);
        const float2 b1 = *(const float2*)(pa + W + ib);
        const float2 a2 = *(const float2*)(pb + ia);
        const float2 b2 = *(const float2*)(pb + ib);
        const float2 a3 = *(const float2*)(pb + W + ia);
        const float2 b3 = *(const float2*)(pb + W + ib);
        const float2 c0 = *(const float2*)(pa + HW + ia);
        const float2 e0 = *(const float2*)(pa + HW + ib);
        const float2 c1 = *(const float2*)(pa + HW + W + ia);
        const float2 e1 = *(const float2*)(pa + HW + W + ib);
        const float2 c2 = *(const float2*)(pb + HW + ia);
        const float2 e2 = *(const float2*)(pb + HW + ib);
        const float2 c3 = *(const float2*)(pb + HW + W + ia);
        const float2 e3 = *(const float2*)(pb + HW + W + ib);
        __builtin_amdgcn_sched_barrier(0);
        const float dA0 = a0.x * xp.z + a0.y * xp.w + b0.x * xq.x + b0.y * xq.y;
        const float dA1 = a1.x * xp.z + a1.y * xp.w + b1.x * xq.x + b1.y * xq.y;
        const float dA2 = a2.x * xp.z + a2.y * xp.w + b2.x * xq.x + b2.y * xq.y;
        const float dA3 = a3.x * xp.z + a3.y * xp.w + b3.x * xq.x + b3.y * xq.y;
        const float dB0 = c0.x * xp.z + c0.y * xp.w + e0.x * xq.x + e0.y * xq.y;
        const float dB1 = c1.x * xp.z + c1.y * xp.w + e1.x * xq.x + e1.y * xq.y;
        const float dB2 = c2.x * xp.z + c2.y * xp.w + e2.x * xq.x + e2.y * xq.y;
        const float dB3 = c3.x * xp.z + c3.y * xp.w + e3.x * xq.x + e3.y * xq.y;
        o0 = yA.z * dA0 + yA.w * dA1 + yB.x * dA2 + yB.y * dA3;
        o1 = yA.z * dB0 + yA.w * dB1 + yB.x * dB2 + yB.y * dB3;
    }

    // out[(r, 2cp, bin)] and out[(r, 2cp+1, bin)]
    float* const obase = out + (size_t)r * ROI_ELEMS + (size_t)(2 * cp) * BINS + bin;
    obase[0]    = o0;
    obase[BINS] = o1;
}

extern "C" void kernel_launch(void* const* d_in, const int* in_sizes, int n_in,
                              void* d_out, int out_size, void* d_ws, size_t ws_size,
                              hipStream_t stream) {
    const float* x2    = (const float*)d_in[0];
    const float* x3    = (const float*)d_in[1];
    const float* x4    = (const float*)d_in[2];
    const float* x5    = (const float*)d_in[3];
    const float* boxes = (const float*)d_in[4];
    float* out = (float*)d_out;

    dim3 grid(NROI, NCHUNK);
    roi_pool_kernel<<<grid, 256, 0, stream>>>(x2, x3, x4, x5, boxes, out);
}